// Round 8
// baseline (56.999 us; speedup 1.0000x reference)
//
#include <hip/hip_runtime.h>

#define NMAPS 8
#define BATCH 32
#define DLEN  150528              // 3*224*224
#define D4    (DLEN / 4)          // 37632 float4 per (map, batch) row
#define NPAIR 36                  // i<=j pairs incl diagonal (diag = norm^2)
#define CHUNKS 32                 // blocks per batch element
#define TPB   256
#define JSTRIDE (CHUNKS * TPB)    // 8192 float4
#define NITEMS (BATCH * NPAIR)    // 1152
#define NBLOCKS (BATCH * CHUNKS)  // 1024

typedef float floatx4 __attribute__((ext_vector_type(4)));

// Fused kernel: 36 unique pairwise dots per batch element (single pass over
// the 154 MB input, non-temporal float4 loads), then last-block-done tail
// computes the cosine-similarity mean in-place (no second dispatch).
// ws layout: partial[CHUNKS][NITEMS] floats, then counter (1 uint).
__global__ __launch_bounds__(TPB) void gram_fused_kernel(const float* __restrict__ xf,
                                                         float* __restrict__ partial,
                                                         unsigned int* __restrict__ counter,
                                                         float* __restrict__ out) {
    const int b     = blockIdx.x;   // 0..31
    const int chunk = blockIdx.y;   // 0..31
    const int tid   = threadIdx.x;
    const int lane  = tid & 63;
    const int wave  = tid >> 6;

    const floatx4* xb = reinterpret_cast<const floatx4*>(xf) + (size_t)b * D4;
    const size_t strideI = (size_t)BATCH * D4;   // float4 stride between maps

    float acc[NPAIR];
#pragma unroll
    for (int k = 0; k < NPAIR; ++k) acc[k] = 0.0f;

#pragma unroll 1
    for (int j = chunk * TPB + tid; j < D4; j += JSTRIDE) {
        floatx4 v[NMAPS];
#pragma unroll
        for (int i = 0; i < NMAPS; ++i)
            v[i] = __builtin_nontemporal_load(&xb[(size_t)i * strideI + j]);
        int k = 0;
#pragma unroll
        for (int i = 0; i < NMAPS; ++i) {
#pragma unroll
            for (int jj = i; jj < NMAPS; ++jj) {
                acc[k] += v[i].x * v[jj].x + v[i].y * v[jj].y +
                          v[i].z * v[jj].z + v[i].w * v[jj].w;
                ++k;
            }
        }
    }

    // wave shuffle reduce, then cross-wave LDS reduce
    __shared__ float red[TPB / 64][NPAIR];
#pragma unroll
    for (int k = 0; k < NPAIR; ++k) {
        float s = acc[k];
#pragma unroll
        for (int off = 32; off > 0; off >>= 1) s += __shfl_down(s, off, 64);
        if (lane == 0) red[wave][k] = s;
    }
    __syncthreads();
    if (tid < NPAIR) {
        // layout: partial[chunk][b*36+k] -> tail reads coalesced over items
        partial[(size_t)chunk * NITEMS + b * NPAIR + tid] =
            red[0][tid] + red[1][tid] + red[2][tid] + red[3][tid];
    }

    // ---- last-block-done tail ----
    __syncthreads();
    __shared__ unsigned int old_s;
    if (tid == 0) {
        __threadfence();   // release: partial stores visible device-wide
        old_s = atomicAdd(counter, 1u);
    }
    __syncthreads();
    if (old_s != NBLOCKS - 1) return;   // not the last block
    __threadfence();       // acquire side

    __shared__ float dots_s[NITEMS];          // [b][k]
    __shared__ float norms[BATCH][NMAPS];

    for (int item = tid; item < NITEMS; item += TPB) {
        float s = 0.0f;
#pragma unroll
        for (int c = 0; c < CHUNKS; ++c)
            s += __hip_atomic_load(&partial[(size_t)c * NITEMS + item],
                                   __ATOMIC_RELAXED, __HIP_MEMORY_SCOPE_AGENT);
        dots_s[item] = s;
    }
    __syncthreads();
    {
        int bb = tid >> 3, i = tid & 7;             // 256 = 32*8
        int diag = 8 * i - (i * (i - 1)) / 2;
        norms[bb][i] = sqrtf(dots_s[bb * NPAIR + diag]);
    }
    __syncthreads();

    float sum = 0.0f;
    for (int item = tid; item < 28 * BATCH; item += TPB) {
        int p = item >> 5;   // pair 0..27
        int bb = item & 31;
        int i = 0, rem = p;
        while (rem >= 7 - i) { rem -= 7 - i; ++i; }
        int j = i + 1 + rem;
        int k = 8 * i - (i * (i - 1)) / 2 + (j - i);
        float d   = fabsf(dots_s[bb * NPAIR + k]);
        float den = fmaxf(norms[bb][i] * norms[bb][j], 1e-8f);
        sum += d / den;
    }
    __shared__ float red2[TPB / 64];
#pragma unroll
    for (int off = 32; off > 0; off >>= 1) sum += __shfl_down(sum, off, 64);
    if (lane == 0) red2[wave] = sum;
    __syncthreads();
    if (tid == 0)
        out[0] = (red2[0] + red2[1] + red2[2] + red2[3]) / (28.0f * BATCH);
}

extern "C" void kernel_launch(void* const* d_in, const int* in_sizes, int n_in,
                              void* d_out, int out_size, void* d_ws, size_t ws_size,
                              hipStream_t stream) {
    const float* x       = (const float*)d_in[0];
    float*       out     = (float*)d_out;
    float*       partial = (float*)d_ws;   // CHUNKS*NITEMS floats = 147456 B
    unsigned int* counter = (unsigned int*)((char*)d_ws + (size_t)CHUNKS * NITEMS * sizeof(float));

    hipMemsetAsync(counter, 0, sizeof(unsigned int), stream);

    dim3 grid(BATCH, CHUNKS);
    gram_fused_kernel<<<grid, TPB, 0, stream>>>(x, partial, counter, out);
}

// Round 9
// 49.826 us; speedup vs baseline: 1.1440x; 1.1440x over previous
//
#include <hip/hip_runtime.h>
#include <stdint.h>

#define NMAPS 8
#define BATCH 32
#define DLEN  150528               // 3*224*224 floats per (map,b) row
#define NPAIR 36                   // i<=j pairs incl diagonal (diag = norm^2)
#define NC    21                   // segments per (map,b) row
#define TILES 7                    // tiles per block
#define TILE_F 1024                // floats per map per tile (4 KB)
#define SEG_F (TILES * TILE_F)     // 7168 floats per block per map (21*7168=150528)
#define TPB   512                  // 8 waves: wave w owns map w
#define NITEMS (BATCH * NPAIR)     // 1152

// async global->LDS: 16B/lane, lane i lands at lds_dst + i*16.
// gsrc is PER-LANE (includes lane*16B); lds_dst must be wave-uniform.
__device__ __forceinline__ void stage1k(const float* gsrc, float* lds_dst) {
    __builtin_amdgcn_global_load_lds(
        (const __attribute__((address_space(1))) uint32_t*)gsrc,
        (__attribute__((address_space(3))) uint32_t*)lds_dst, 16, 0, 0);
}

// Kernel 1: wave-per-map contiguous streaming. Wave w reads ONLY map w in
// back-to-back 4KB bursts (copy-like per-wave access stream). Double-buffered
// LDS, counted vmcnt (prefetch stays in flight across raw s_barrier).
__global__ __launch_bounds__(TPB) void gram_kernel(const float* __restrict__ xf,
                                                   float* __restrict__ partial) {
    const int b    = blockIdx.x;    // 0..31
    const int c    = blockIdx.y;    // 0..20
    const int tid  = threadIdx.x;
    const int lane = tid & 63;
    const int wv   = tid >> 6;      // wave 0..7 == map index

    __shared__ float buf[2][NMAPS][TILE_F];   // 64 KB double buffer
    __shared__ float red[TPB / 64][NPAIR];

    // per-lane global source for this wave's map, this block's segment
    const float* xsrc = xf + ((size_t)wv * BATCH + b) * DLEN
                           + (size_t)c * SEG_F + lane * 4;

    float acc[NPAIR];
#pragma unroll
    for (int k = 0; k < NPAIR; ++k) acc[k] = 0.0f;

    // prologue: stage tile 0 into buf[0]  (4 x 1KB contiguous per wave)
#pragma unroll
    for (int s = 0; s < 4; ++s)
        stage1k(xsrc + 0 * TILE_F + s * 256, &buf[0][wv][s * 256]);

#pragma unroll 1
    for (int t = 0; t < TILES; ++t) {
        if (t < TILES - 1) {
            // prefetch next tile into the other buffer
#pragma unroll
            for (int s = 0; s < 4; ++s)
                stage1k(xsrc + (size_t)(t + 1) * TILE_F + s * 256,
                        &buf[(t + 1) & 1][wv][s * 256]);
            // wait until only the 4 newest (prefetch) loads are outstanding
            asm volatile("s_waitcnt vmcnt(4)" ::: "memory");
        } else {
            asm volatile("s_waitcnt vmcnt(0)" ::: "memory");
        }
        __builtin_amdgcn_sched_barrier(0);
        __builtin_amdgcn_s_barrier();      // tile t fully in LDS (all waves)
        asm volatile("" ::: "memory");

        // compute on tile t: each thread takes 2 floats per map
        {
            const float2* bb = (const float2*)&buf[t & 1][0][0];
            float2 v[NMAPS];
#pragma unroll
            for (int m = 0; m < NMAPS; ++m) v[m] = bb[m * (TILE_F / 2) + tid];
            int k = 0;
#pragma unroll
            for (int i = 0; i < NMAPS; ++i) {
#pragma unroll
                for (int jj = i; jj < NMAPS; ++jj) {
                    acc[k] += v[i].x * v[jj].x + v[i].y * v[jj].y;
                    ++k;
                }
            }
        }
        asm volatile("" ::: "memory");
        __builtin_amdgcn_s_barrier();      // readers done before overwrite
    }

    // wave shuffle reduce, then cross-wave LDS reduce (8 waves)
#pragma unroll
    for (int k = 0; k < NPAIR; ++k) {
        float s = acc[k];
#pragma unroll
        for (int off = 32; off > 0; off >>= 1) s += __shfl_down(s, off, 64);
        if (lane == 0) red[wv][k] = s;
    }
    __syncthreads();
    if (tid < NPAIR) {
        float t = 0.0f;
#pragma unroll
        for (int w = 0; w < TPB / 64; ++w) t += red[w][tid];
        // layout: partial[c][b*36+k]
        partial[(size_t)c * NITEMS + b * NPAIR + tid] = t;
    }
}

// Kernel 2: sum partials over the 21 segments, then cosine epilogue.
__global__ __launch_bounds__(256) void finalize_kernel(const float* __restrict__ partial,
                                                       float* __restrict__ out) {
    const int tid = threadIdx.x;
    __shared__ float dots_s[NITEMS];          // [b][k]
    __shared__ float norms[BATCH][NMAPS];

    for (int item = tid; item < NITEMS; item += 256) {
        float s = 0.0f;
#pragma unroll
        for (int c = 0; c < NC; ++c) s += partial[(size_t)c * NITEMS + item];
        dots_s[item] = s;
    }
    __syncthreads();
    {
        int bb = tid >> 3, i = tid & 7;             // 256 = 32*8
        int diag = 8 * i - (i * (i - 1)) / 2;
        norms[bb][i] = sqrtf(dots_s[bb * NPAIR + diag]);
    }
    __syncthreads();

    float sum = 0.0f;
    for (int item = tid; item < 28 * BATCH; item += 256) {
        int p = item >> 5;   // pair 0..27
        int bb = item & 31;
        int i = 0, rem = p;
        while (rem >= 7 - i) { rem -= 7 - i; ++i; }
        int j = i + 1 + rem;
        int k = 8 * i - (i * (i - 1)) / 2 + (j - i);
        float d   = fabsf(dots_s[bb * NPAIR + k]);
        float den = fmaxf(norms[bb][i] * norms[bb][j], 1e-8f);
        sum += d / den;
    }

    const int lane = tid & 63, wave = tid >> 6;
    __shared__ float red2[4];
#pragma unroll
    for (int off = 32; off > 0; off >>= 1) sum += __shfl_down(sum, off, 64);
    if (lane == 0) red2[wave] = sum;
    __syncthreads();
    if (tid == 0)
        out[0] = (red2[0] + red2[1] + red2[2] + red2[3]) / (28.0f * BATCH);
}

extern "C" void kernel_launch(void* const* d_in, const int* in_sizes, int n_in,
                              void* d_out, int out_size, void* d_ws, size_t ws_size,
                              hipStream_t stream) {
    const float* x       = (const float*)d_in[0];
    float*       out     = (float*)d_out;
    float*       partial = (float*)d_ws;   // NC*NITEMS floats = 96768 B

    dim3 grid(BATCH, NC);
    gram_kernel<<<grid, TPB, 0, stream>>>(x, partial);
    finalize_kernel<<<1, 256, 0, stream>>>(partial, out);
}